// Round 1
// baseline (264.532 us; speedup 1.0000x reference)
//
#include <hip/hip_runtime.h>
#include <hip/hip_fp16.h>
#include <math.h>

#define NN 100000
#define NE 1000000
#define CAP 32        // bucket capacity per node; degrees ~Poisson(10), max ~27
#define OVCAP 4096    // overflow list capacity (correct fallback, ~never used)
#define NEB 3907      // ceil(NE/256) bucket blocks
#define NTILE 6250    // NN/16 MFMA row-tiles
#define RB 256        // softmax reduction grid
#define GB1 512       // GEMM-role blocks inside the fused kernel
// H = 64. R20: bucket scatter is latency-bound (12.5% HBM, 0.5% VALU) -> hide
// GEMM1 under it via block-role fusion. xw is now UNFOLDED X@W1; deg is
// accumulated atomically at bucket time; dinv = rsqrt(deg+1) in-place; the
// layer-1 gather folds dinv[src] per edge. Layer-2 path unchanged (xw2 is
// still dinv-prefolded at write time by k_gather_gemm2).
// R14 LESSON: gather input and GEMM output must be DISTINCT buffers.
// R16 LESSON: src-sliced gather falsified — dense 4-deep unroll is the best form.

typedef _Float16 half8 __attribute__((ext_vector_type(8)));
typedef float f32x4 __attribute__((ext_vector_type(4)));

// ---------------- W staging: fragment layout in LDS (k=(s*32+q*8+j), n=t*16+l15) ----------------

__device__ __forceinline__ void stage_B_lds(const float* __restrict__ W,
                                            _Float16* __restrict__ ldsB) {
  for (int u = threadIdx.x; u < 512; u += 256) {
    int slane = u & 63, ts = u >> 6;
    int t = ts >> 1, s = ts & 1;
    int qq = slane >> 4, ll = slane & 15;
#pragma unroll
    for (int j = 0; j < 8; ++j)
      ldsB[u * 8 + j] = (_Float16)W[(s * 32 + qq * 8 + j) * 64 + t * 16 + ll];
  }
}

// ---------------- fused bucket build + GEMM1 ----------------
// blocks [0,GB1): xw = X@W1 (fp16, UNFOLDED — no bucket dependency)
// blocks [GB1, GB1+NEB): edge scatter into buckets + atomic deg accumulate
// GEMM blocks dispatch first (2/CU), bucket waves fill the remaining slots and
// the scatter latency hides the GEMM compute.

__global__ __launch_bounds__(256) void k_bucket_gemm1(const int* __restrict__ src,
                                                      const int* __restrict__ dst,
                                                      const float* __restrict__ ew,
                                                      const float* __restrict__ X,
                                                      const float* __restrict__ W1,
                                                      int* __restrict__ cnt,
                                                      float* __restrict__ deg,
                                                      int2* __restrict__ bucket,
                                                      int4* __restrict__ ovf,
                                                      int* __restrict__ ovf_n,
                                                      __half* __restrict__ Y) {
  __shared__ _Float16 ldsB[4096];
  if (blockIdx.x >= GB1) {
    // ---- bucket role ----
    int e = (blockIdx.x - GB1) * 256 + threadIdx.x;
    if (e < NE) {
      int s = src[e];
      int d = dst[e];
      float w = ew[e];
      int pos = atomicAdd(&cnt[d], 1);
      unsafeAtomicAdd(&deg[d], w);
      if (pos < CAP) {
        bucket[d * CAP + pos] = make_int2(s, __float_as_int(w));
      } else {
        int t = atomicAdd(ovf_n, 1);
        if (t < OVCAP) ovf[t] = make_int4(s, d, __float_as_int(w), 0);
      }
    }
    return;
  }
  // ---- GEMM role: 16x16x32_f16; A: m=lane&15, k=(lane>>4)*8+j;
  // C/D: col=lane&15, row=q*4+reg [m89-verified] ----
  stage_B_lds(W1, ldsB);
  __syncthreads();
  int lane = threadIdx.x & 63;
  int l15 = lane & 15, q = lane >> 4;
  half8 bfr[4][2];
#pragma unroll
  for (int t = 0; t < 4; ++t)
#pragma unroll
    for (int s = 0; s < 2; ++s)
      bfr[t][s] = *(half8*)&ldsB[((t * 2 + s) * 64 + lane) * 8];

  int wid = blockIdx.x * 4 + (threadIdx.x >> 6);
  for (int tile = wid; tile < NTILE; tile += GB1 * 4) {
    int row = tile * 16 + l15;
    f32x4 acc[4] = {{0.f,0.f,0.f,0.f},{0.f,0.f,0.f,0.f},
                    {0.f,0.f,0.f,0.f},{0.f,0.f,0.f,0.f}};
#pragma unroll
    for (int s = 0; s < 2; ++s) {
      const float* ap = X + (size_t)row * 64 + s * 32 + q * 8;
      float4 a0 = *(const float4*)ap;
      float4 a1 = *(const float4*)(ap + 4);
      half8 af;
      af[0] = (_Float16)a0.x; af[1] = (_Float16)a0.y;
      af[2] = (_Float16)a0.z; af[3] = (_Float16)a0.w;
      af[4] = (_Float16)a1.x; af[5] = (_Float16)a1.y;
      af[6] = (_Float16)a1.z; af[7] = (_Float16)a1.w;
#pragma unroll
      for (int t = 0; t < 4; ++t)
        acc[t] = __builtin_amdgcn_mfma_f32_16x16x32_f16(af, bfr[t][s], acc[t], 0, 0, 0);
    }
#pragma unroll
    for (int r = 0; r < 4; ++r) {
      int rw = tile * 16 + q * 4 + r;
#pragma unroll
      for (int t = 0; t < 4; ++t)
        Y[(size_t)rw * 64 + t * 16 + l15] = __float2half(acc[t][r]);
    }
  }
}

// ---------------- dinv = rsqrt(deg + 1), in place over deg ----------------

__global__ __launch_bounds__(256) void k_dinv(float* __restrict__ deg) {
  int i = blockIdx.x * 256 + threadIdx.x;
  if (i < NN) deg[i] = 1.0f / sqrtf(deg[i] + 1.0f);
}

// ---------------- gather core: 16 lanes/node, fp16 rows ----------------
// Dense 4-deep unconditional unroll (R15 form — best measured).
// FOLD=true: per-edge weight *= dinv[src] (layer-1; xw unfolded), self term
// scaled by selfw=dinv[node]. FOLD=false: weights raw (layer-2; xw2 prefolded).

__device__ __forceinline__ float4 h4load(const __half* p) {
  float2 raw = *(const float2*)p;  // 4 halfs in one dwordx2
  __half2 a = *(__half2*)&raw.x;
  __half2 b = *(__half2*)&raw.y;
  float2 fa = __half22float2(a), fb = __half22float2(b);
  return make_float4(fa.x, fa.y, fb.x, fb.y);
}

template <bool FOLD>
__device__ __forceinline__ float4 gather_node(const __half* __restrict__ xw,
                                              const int* __restrict__ cnt,
                                              const int2* __restrict__ bucket,
                                              const int4* __restrict__ ovf,
                                              const int* __restrict__ ovf_n,
                                              const float* __restrict__ dinv,
                                              int node, int l, float selfw) {
  int c = cnt[node];
  int cc = c < CAP ? c : CAP;
  const int4* bk4 = (const int4*)(bucket + (size_t)node * CAP);
  float4 acc = make_float4(0.f, 0.f, 0.f, 0.f);

  int j = 0;
  for (; j + 4 <= cc; j += 4) {
    int4 pa = bk4[j >> 1];
    int4 pb = bk4[(j >> 1) + 1];
    const float4 x0 = h4load(xw + (size_t)pa.x * 64 + l * 4);
    const float4 x1 = h4load(xw + (size_t)pa.z * 64 + l * 4);
    const float4 x2 = h4load(xw + (size_t)pb.x * 64 + l * 4);
    const float4 x3 = h4load(xw + (size_t)pb.z * 64 + l * 4);
    float v0 = __int_as_float(pa.y);
    float v1 = __int_as_float(pa.w);
    float v2 = __int_as_float(pb.y);
    float v3 = __int_as_float(pb.w);
    if (FOLD) {
      v0 *= dinv[pa.x]; v1 *= dinv[pa.z];
      v2 *= dinv[pb.x]; v3 *= dinv[pb.z];
    }
    acc.x = fmaf(x0.x, v0, acc.x); acc.y = fmaf(x0.y, v0, acc.y);
    acc.z = fmaf(x0.z, v0, acc.z); acc.w = fmaf(x0.w, v0, acc.w);
    acc.x = fmaf(x1.x, v1, acc.x); acc.y = fmaf(x1.y, v1, acc.y);
    acc.z = fmaf(x1.z, v1, acc.z); acc.w = fmaf(x1.w, v1, acc.w);
    acc.x = fmaf(x2.x, v2, acc.x); acc.y = fmaf(x2.y, v2, acc.y);
    acc.z = fmaf(x2.z, v2, acc.z); acc.w = fmaf(x2.w, v2, acc.w);
    acc.x = fmaf(x3.x, v3, acc.x); acc.y = fmaf(x3.y, v3, acc.y);
    acc.z = fmaf(x3.z, v3, acc.z); acc.w = fmaf(x3.w, v3, acc.w);
  }
  const int2* bk = (const int2*)bk4;
  for (; j < cc; ++j) {
    int2 E = bk[j];
    const float4 xa = h4load(xw + (size_t)E.x * 64 + l * 4);
    float v = __int_as_float(E.y);
    if (FOLD) v *= dinv[E.x];
    acc.x = fmaf(xa.x, v, acc.x); acc.y = fmaf(xa.y, v, acc.y);
    acc.z = fmaf(xa.z, v, acc.z); acc.w = fmaf(xa.w, v, acc.w);
  }
  if (c > CAP) {
    int on = ovf_n[0]; if (on > OVCAP) on = OVCAP;
    for (int t = 0; t < on; ++t) {
      int4 o = ovf[t];
      if (o.y == node) {
        const float4 xa = h4load(xw + (size_t)o.x * 64 + l * 4);
        float v = __int_as_float(o.z);
        if (FOLD) v *= dinv[o.x];
        acc.x = fmaf(xa.x, v, acc.x); acc.y = fmaf(xa.y, v, acc.y);
        acc.z = fmaf(xa.z, v, acc.z); acc.w = fmaf(xa.w, v, acc.w);
      }
    }
  }
  // self-loop (weight 1, scaled by selfw; outer *dinv[dst] completes dinv^2)
  const float4 xs = h4load(xw + (size_t)node * 64 + l * 4);
  acc.x = fmaf(xs.x, selfw, acc.x); acc.y = fmaf(xs.y, selfw, acc.y);
  acc.z = fmaf(xs.z, selfw, acc.z); acc.w = fmaf(xs.w, selfw, acc.w);
  return acc;
}

// ---------------- fused layer-1 gather + GEMM2 (xw -> xw2) ----------------

__global__ __launch_bounds__(256) void k_gather_gemm2(const __half* __restrict__ xw,
                                                      const float* __restrict__ dinv,
                                                      const int* __restrict__ cnt,
                                                      const int2* __restrict__ bucket,
                                                      const int4* __restrict__ ovf,
                                                      const int* __restrict__ ovf_n,
                                                      const float* __restrict__ b1,
                                                      const float* __restrict__ W2,
                                                      __half* __restrict__ Y) {
  __shared__ _Float16 ldsB[4096];
  __shared__ _Float16 ldsR[16 * 72];
  __shared__ float sdi[16];
  stage_B_lds(W2, ldsB);

  int l = threadIdx.x & 15;
  int g = threadIdx.x >> 4;
  int node = blockIdx.x * 16 + g;
  float di = dinv[node];
  float4 acc = gather_node<true>(xw, cnt, bucket, ovf, ovf_n, dinv, node, l, di);
  const float4 b4 = *(const float4*)(b1 + l * 4);
  _Float16* rp = &ldsR[g * 72 + l * 4];
  rp[0] = (_Float16)fmaxf(fmaf(acc.x, di, b4.x), 0.f);
  rp[1] = (_Float16)fmaxf(fmaf(acc.y, di, b4.y), 0.f);
  rp[2] = (_Float16)fmaxf(fmaf(acc.z, di, b4.z), 0.f);
  rp[3] = (_Float16)fmaxf(fmaf(acc.w, di, b4.w), 0.f);
  if (l == 0) sdi[g] = di;
  __syncthreads();

  int lane = threadIdx.x & 63;
  int l15 = lane & 15, q = lane >> 4;
  int t = threadIdx.x >> 6;  // this wave's col-tile
  half8 a0 = *(half8*)&ldsR[l15 * 72 + q * 8];
  half8 a1 = *(half8*)&ldsR[l15 * 72 + 32 + q * 8];
  half8 bf0 = *(half8*)&ldsB[((t * 2 + 0) * 64 + lane) * 8];
  half8 bf1 = *(half8*)&ldsB[((t * 2 + 1) * 64 + lane) * 8];
  f32x4 acc2 = {0.f, 0.f, 0.f, 0.f};
  acc2 = __builtin_amdgcn_mfma_f32_16x16x32_f16(a0, bf0, acc2, 0, 0, 0);
  acc2 = __builtin_amdgcn_mfma_f32_16x16x32_f16(a1, bf1, acc2, 0, 0, 0);
#pragma unroll
  for (int r = 0; r < 4; ++r) {
    int rw = blockIdx.x * 16 + q * 4 + r;
    float dv = sdi[q * 4 + r];
    Y[(size_t)rw * 64 + t * 16 + l15] = __float2half(acc2[r] * dv);
  }
}

// ---------------- layer-2 aggregation + heads + per-block max partial ----------------

__global__ __launch_bounds__(256) void k_gather_l2_heads(const __half* __restrict__ xw2,
                                                         const float* __restrict__ dinv,
                                                         const int* __restrict__ cnt,
                                                         const int2* __restrict__ bucket,
                                                         const int4* __restrict__ ovf,
                                                         const int* __restrict__ ovf_n,
                                                         const float* __restrict__ b2,
                                                         const float* __restrict__ Wn,
                                                         const float* __restrict__ bn,
                                                         const float* __restrict__ Wr,
                                                         const float* __restrict__ br,
                                                         float* __restrict__ logits,
                                                         float* __restrict__ rr,
                                                         float* __restrict__ part) {
  __shared__ float s[256];
  int l = threadIdx.x & 15;
  int node = blockIdx.x * 16 + (threadIdx.x >> 4);
  float4 acc = gather_node<false>(xw2, cnt, bucket, ovf, ovf_n, dinv, node, l, 1.0f);
  float di = dinv[node];
  const float4 b4 = *(const float4*)(b2 + l * 4);
  float4 r;
  r.x = fmaxf(fmaf(acc.x, di, b4.x), 0.f); r.y = fmaxf(fmaf(acc.y, di, b4.y), 0.f);
  r.z = fmaxf(fmaf(acc.z, di, b4.z), 0.f); r.w = fmaxf(fmaf(acc.w, di, b4.w), 0.f);
  const float4 wn4 = *(const float4*)(Wn + l * 4);
  const float4 wr4 = *(const float4*)(Wr + l * 4);
  float an = r.x * wn4.x + r.y * wn4.y + r.z * wn4.z + r.w * wn4.w;
  float ar = r.x * wr4.x + r.y * wr4.y + r.z * wr4.z + r.w * wr4.w;
#pragma unroll
  for (int m = 8; m > 0; m >>= 1) {
    an += __shfl_xor(an, m, 64);
    ar += __shfl_xor(ar, m, 64);
  }
  float lg = an + bn[0];
  if (l == 0) {
    logits[node] = lg;
    float xr = ar + br[0];
    rr[node] = 0.01f / (1.0f + expf(-xr));
  }
  // block max of 16 logits (dups across lanes are harmless)
  s[threadIdx.x] = lg;
  __syncthreads();
  for (int w = 128; w > 0; w >>= 1) {
    if (threadIdx.x < w) s[threadIdx.x] = fmaxf(s[threadIdx.x], s[threadIdx.x + w]);
    __syncthreads();
  }
  if (threadIdx.x == 0) part[blockIdx.x] = s[0];
}

// ---------------- softmax: per-block global-max re-reduce + exp + atomic sum ----------------

__global__ __launch_bounds__(256) void k_sexp(const float* __restrict__ logits,
                                              const float* __restrict__ part,
                                              float* __restrict__ sel,
                                              float* __restrict__ gsum) {
  __shared__ float s[256];
  float m = -INFINITY;
  for (int i = threadIdx.x; i < NTILE; i += 256) m = fmaxf(m, part[i]);
  s[threadIdx.x] = m;
  __syncthreads();
  for (int w = 128; w > 0; w >>= 1) {
    if (threadIdx.x < w) s[threadIdx.x] = fmaxf(s[threadIdx.x], s[threadIdx.x + w]);
    __syncthreads();
  }
  float gm = s[0];
  __syncthreads();
  float acc = 0.0f;
  for (int i = blockIdx.x * 256 + threadIdx.x; i < NN; i += RB * 256) {
    float e = expf(logits[i] - gm);
    sel[i] = e;
    acc += e;
  }
  s[threadIdx.x] = acc;
  __syncthreads();
  for (int w = 128; w > 0; w >>= 1) {
    if (threadIdx.x < w) s[threadIdx.x] += s[threadIdx.x + w];
    __syncthreads();
  }
  if (threadIdx.x == 0) unsafeAtomicAdd(gsum, s[0]);  // 256 funnel atomics ~4us
}

__global__ __launch_bounds__(256) void k_snorm(float* __restrict__ sel,
                                               const float* __restrict__ gsum) {
  int i = blockIdx.x * 256 + threadIdx.x;
  if (i < NN) sel[i] *= (1.0f / gsum[0]);
}

// ---------------- launch ----------------

extern "C" void kernel_launch(void* const* d_in, const int* in_sizes, int n_in,
                              void* d_out, int out_size, void* d_ws, size_t ws_size,
                              hipStream_t stream) {
  const float* x  = (const float*)d_in[0];
  const int*   ei = (const int*)d_in[1];   // [2, E]: src row then dst row
  const float* ew = (const float*)d_in[2];
  const float* W1 = (const float*)d_in[3];
  const float* b1 = (const float*)d_in[4];
  const float* W2 = (const float*)d_in[5];
  const float* b2 = (const float*)d_in[6];
  const float* Wn = (const float*)d_in[7];
  const float* bn = (const float*)d_in[8];
  const float* Wr = (const float*)d_in[9];
  const float* br = (const float*)d_in[10];
  const int* src = ei;
  const int* dst = ei + NE;

  // ws layout (byte offsets, all regions 16B-aligned, total 52,490,544 B)
  char* wsb = (char*)d_ws;
  __half* xw     = (__half*)wsb;                        // 12,800,000 B (layer-1 features, UNFOLDED)
  __half* xw2    = (__half*)(wsb + 12800000);           // 12,800,000 B (layer-2 features, prefolded)
  float*  logits = (float*)(wsb + 25600000);            // 400,000 B
  int2*   bucket = (int2*)(wsb + 26000000);             // 25,600,000 B
  int4*   ovf    = (int4*)(wsb + 51600000);             // 65,536 B
  int*    cnt    = (int*)(wsb + 51665536);              // 400,000 B -- memset from here
  float*  deg    = (float*)(wsb + 52065536);            // 400,000 B (becomes dinv in place)
  int*    ovf_n  = (int*)(wsb + 52465536);              // 4 B
  float*  gsum   = (float*)(wsb + 52465540);            // 4 B       -- memset to here
  float*  part1  = (float*)(wsb + 52465544);            // 25,000 B (6250 floats)

  float* sel = (float*)d_out;                           // node_selector [N]
  float* rr  = (float*)d_out + NN;                      // rescue_ratios [N]

  int gN = (NN + 255) / 256;

  // zero cnt + deg + ovf_n + gsum in one memset
  hipMemsetAsync(cnt, 0, (size_t)(2 * NN + 2) * 4, stream);

  // ---- fused bucket build + GEMM1 (scatter latency hides the MFMA work) ----
  k_bucket_gemm1<<<GB1 + NEB, 256, 0, stream>>>(src, dst, ew, x, W1,
                                                cnt, deg, bucket, ovf, ovf_n, xw);

  // ---- deg -> dinv in place ----
  k_dinv<<<gN, 256, 0, stream>>>(deg);

  // ---- fused layer-1 gather (dinv[src] folded per edge) + gemm2: xw -> xw2 ----
  k_gather_gemm2<<<NTILE, 256, 0, stream>>>(xw, deg, cnt, bucket, ovf, ovf_n,
                                            b1, W2, xw2);

  // ---- layer 2 gather + heads + max partials ----
  k_gather_l2_heads<<<NTILE, 256, 0, stream>>>(xw2, deg, cnt, bucket, ovf, ovf_n,
                                               b2, Wn, bn, Wr, br, logits, rr, part1);

  // ---- softmax ----
  k_sexp<<<RB, 256, 0, stream>>>(logits, part1, sel, gsum);
  k_snorm<<<gN, 256, 0, stream>>>(sel, gsum);
}

// Round 2
// 227.862 us; speedup vs baseline: 1.1609x; 1.1609x over previous
//
#include <hip/hip_runtime.h>
#include <hip/hip_fp16.h>
#include <math.h>

#define NN 100000
#define NE 1000000
#define CAP 32        // bucket capacity per node; degrees ~Poisson(10), max ~27
#define OVCAP 4096    // overflow list capacity (correct fallback, ~never used)
#define NEB 3907      // ceil(NE/256) bucket blocks
#define NTILE 6250    // NN/16 MFMA row-tiles
#define RB 256        // softmax reduction grid
#define GB1 512       // GEMM-role blocks inside the fused kernel
// H = 64. R20: bucket scatter is latency-bound -> hide GEMM1 under it via
// block-role fusion (xw = UNFOLDED X@W1, no bucket dependency).
// R21 LESSON: per-edge unsafeAtomicAdd(&deg[d]) cost ~30us (+43MB writebacks,
// fused 70->104us). dinv is now recovered from bucket weights post-build by a
// 4-lane/node walk (~5us). Layer-1 gather folds dinv[src] per edge (measured
// FREE in R21: rest-of-pipeline identical with/without FOLD).
// R14 LESSON: gather input and GEMM output must be DISTINCT buffers.
// R16 LESSON: src-sliced gather falsified — dense 4-deep unroll is the best form.

typedef _Float16 half8 __attribute__((ext_vector_type(8)));
typedef float f32x4 __attribute__((ext_vector_type(4)));

// ---------------- W staging: fragment layout in LDS (k=(s*32+q*8+j), n=t*16+l15) ----------------

__device__ __forceinline__ void stage_B_lds(const float* __restrict__ W,
                                            _Float16* __restrict__ ldsB) {
  for (int u = threadIdx.x; u < 512; u += 256) {
    int slane = u & 63, ts = u >> 6;
    int t = ts >> 1, s = ts & 1;
    int qq = slane >> 4, ll = slane & 15;
#pragma unroll
    for (int j = 0; j < 8; ++j)
      ldsB[u * 8 + j] = (_Float16)W[(s * 32 + qq * 8 + j) * 64 + t * 16 + ll];
  }
}

// ---------------- fused bucket build + GEMM1 ----------------
// blocks [0,GB1): xw = X@W1 (fp16, UNFOLDED — no bucket dependency)
// blocks [GB1, GB1+NEB): edge scatter into buckets (ONE atomic + one 8B store
// per edge — the measured-floor form). GEMM blocks dispatch first, bucket
// waves fill remaining slots; scatter latency hides the MFMA work.

__global__ __launch_bounds__(256) void k_bucket_gemm1(const int* __restrict__ src,
                                                      const int* __restrict__ dst,
                                                      const float* __restrict__ ew,
                                                      const float* __restrict__ X,
                                                      const float* __restrict__ W1,
                                                      int* __restrict__ cnt,
                                                      int2* __restrict__ bucket,
                                                      int4* __restrict__ ovf,
                                                      int* __restrict__ ovf_n,
                                                      __half* __restrict__ Y) {
  __shared__ _Float16 ldsB[4096];
  if (blockIdx.x >= GB1) {
    // ---- bucket role ----
    int e = (blockIdx.x - GB1) * 256 + threadIdx.x;
    if (e < NE) {
      int s = src[e];
      int d = dst[e];
      float w = ew[e];
      int pos = atomicAdd(&cnt[d], 1);
      if (pos < CAP) {
        bucket[d * CAP + pos] = make_int2(s, __float_as_int(w));
      } else {
        int t = atomicAdd(ovf_n, 1);
        if (t < OVCAP) ovf[t] = make_int4(s, d, __float_as_int(w), 0);
      }
    }
    return;
  }
  // ---- GEMM role: 16x16x32_f16; A: m=lane&15, k=(lane>>4)*8+j;
  // C/D: col=lane&15, row=q*4+reg [m89-verified] ----
  stage_B_lds(W1, ldsB);
  __syncthreads();
  int lane = threadIdx.x & 63;
  int l15 = lane & 15, q = lane >> 4;
  half8 bfr[4][2];
#pragma unroll
  for (int t = 0; t < 4; ++t)
#pragma unroll
    for (int s = 0; s < 2; ++s)
      bfr[t][s] = *(half8*)&ldsB[((t * 2 + s) * 64 + lane) * 8];

  int wid = blockIdx.x * 4 + (threadIdx.x >> 6);
  for (int tile = wid; tile < NTILE; tile += GB1 * 4) {
    int row = tile * 16 + l15;
    f32x4 acc[4] = {{0.f,0.f,0.f,0.f},{0.f,0.f,0.f,0.f},
                    {0.f,0.f,0.f,0.f},{0.f,0.f,0.f,0.f}};
#pragma unroll
    for (int s = 0; s < 2; ++s) {
      const float* ap = X + (size_t)row * 64 + s * 32 + q * 8;
      float4 a0 = *(const float4*)ap;
      float4 a1 = *(const float4*)(ap + 4);
      half8 af;
      af[0] = (_Float16)a0.x; af[1] = (_Float16)a0.y;
      af[2] = (_Float16)a0.z; af[3] = (_Float16)a0.w;
      af[4] = (_Float16)a1.x; af[5] = (_Float16)a1.y;
      af[6] = (_Float16)a1.z; af[7] = (_Float16)a1.w;
#pragma unroll
      for (int t = 0; t < 4; ++t)
        acc[t] = __builtin_amdgcn_mfma_f32_16x16x32_f16(af, bfr[t][s], acc[t], 0, 0, 0);
    }
#pragma unroll
    for (int r = 0; r < 4; ++r) {
      int rw = tile * 16 + q * 4 + r;
#pragma unroll
      for (int t = 0; t < 4; ++t)
        Y[(size_t)rw * 64 + t * 16 + l15] = __float2half(acc[t][r]);
    }
  }
}

// ---------------- dinv from bucket weights: 4 lanes/node, int4 reads ----------------
// Reads only the live prefix of each bucket row (~13MB line-granular), so no
// per-edge atomic is needed anywhere. dinv = rsqrt(1 + sum w).

__global__ __launch_bounds__(256) void k_dinv(const int* __restrict__ cnt,
                                              const int2* __restrict__ bucket,
                                              const int4* __restrict__ ovf,
                                              const int* __restrict__ ovf_n,
                                              float* __restrict__ dinv) {
  int t = threadIdx.x & 3;
  int node = blockIdx.x * 64 + (threadIdx.x >> 2);
  if (node >= NN) return;
  int c = cnt[node];
  int cc = c < CAP ? c : CAP;
  int nq = (cc + 1) >> 1;  // int4 chunks in use (2 edges each)
  const int4* bk4 = (const int4*)(bucket + (size_t)node * CAP);
  float dsum = 0.f;
  for (int j = t; j < nq; j += 4) {
    int4 qv = bk4[j];
    int e0 = 2 * j, e1 = 2 * j + 1;
    if (e0 < cc) dsum += __int_as_float(qv.y);
    if (e1 < cc) dsum += __int_as_float(qv.w);
  }
  dsum += __shfl_xor(dsum, 1, 64);
  dsum += __shfl_xor(dsum, 2, 64);
  if (t == 0) {
    float tot = dsum + 1.0f;  // self-loop weight 1
    if (c > CAP) {
      int on = ovf_n[0]; if (on > OVCAP) on = OVCAP;
      for (int k = 0; k < on; ++k) {
        int4 o = ovf[k];
        if (o.y == node) tot += __int_as_float(o.z);
      }
    }
    dinv[node] = 1.0f / sqrtf(tot);
  }
}

// ---------------- gather core: 16 lanes/node, fp16 rows ----------------
// Dense 4-deep unconditional unroll (R15 form — best measured).
// FOLD=true: per-edge weight *= dinv[src] (layer-1; xw unfolded), self term
// scaled by selfw=dinv[node]. FOLD=false: weights raw (layer-2; xw2 prefolded).

__device__ __forceinline__ float4 h4load(const __half* p) {
  float2 raw = *(const float2*)p;  // 4 halfs in one dwordx2
  __half2 a = *(__half2*)&raw.x;
  __half2 b = *(__half2*)&raw.y;
  float2 fa = __half22float2(a), fb = __half22float2(b);
  return make_float4(fa.x, fa.y, fb.x, fb.y);
}

template <bool FOLD>
__device__ __forceinline__ float4 gather_node(const __half* __restrict__ xw,
                                              const int* __restrict__ cnt,
                                              const int2* __restrict__ bucket,
                                              const int4* __restrict__ ovf,
                                              const int* __restrict__ ovf_n,
                                              const float* __restrict__ dinv,
                                              int node, int l, float selfw) {
  int c = cnt[node];
  int cc = c < CAP ? c : CAP;
  const int4* bk4 = (const int4*)(bucket + (size_t)node * CAP);
  float4 acc = make_float4(0.f, 0.f, 0.f, 0.f);

  int j = 0;
  for (; j + 4 <= cc; j += 4) {
    int4 pa = bk4[j >> 1];
    int4 pb = bk4[(j >> 1) + 1];
    const float4 x0 = h4load(xw + (size_t)pa.x * 64 + l * 4);
    const float4 x1 = h4load(xw + (size_t)pa.z * 64 + l * 4);
    const float4 x2 = h4load(xw + (size_t)pb.x * 64 + l * 4);
    const float4 x3 = h4load(xw + (size_t)pb.z * 64 + l * 4);
    float v0 = __int_as_float(pa.y);
    float v1 = __int_as_float(pa.w);
    float v2 = __int_as_float(pb.y);
    float v3 = __int_as_float(pb.w);
    if (FOLD) {
      v0 *= dinv[pa.x]; v1 *= dinv[pa.z];
      v2 *= dinv[pb.x]; v3 *= dinv[pb.z];
    }
    acc.x = fmaf(x0.x, v0, acc.x); acc.y = fmaf(x0.y, v0, acc.y);
    acc.z = fmaf(x0.z, v0, acc.z); acc.w = fmaf(x0.w, v0, acc.w);
    acc.x = fmaf(x1.x, v1, acc.x); acc.y = fmaf(x1.y, v1, acc.y);
    acc.z = fmaf(x1.z, v1, acc.z); acc.w = fmaf(x1.w, v1, acc.w);
    acc.x = fmaf(x2.x, v2, acc.x); acc.y = fmaf(x2.y, v2, acc.y);
    acc.z = fmaf(x2.z, v2, acc.z); acc.w = fmaf(x2.w, v2, acc.w);
    acc.x = fmaf(x3.x, v3, acc.x); acc.y = fmaf(x3.y, v3, acc.y);
    acc.z = fmaf(x3.z, v3, acc.z); acc.w = fmaf(x3.w, v3, acc.w);
  }
  const int2* bk = (const int2*)bk4;
  for (; j < cc; ++j) {
    int2 E = bk[j];
    const float4 xa = h4load(xw + (size_t)E.x * 64 + l * 4);
    float v = __int_as_float(E.y);
    if (FOLD) v *= dinv[E.x];
    acc.x = fmaf(xa.x, v, acc.x); acc.y = fmaf(xa.y, v, acc.y);
    acc.z = fmaf(xa.z, v, acc.z); acc.w = fmaf(xa.w, v, acc.w);
  }
  if (c > CAP) {
    int on = ovf_n[0]; if (on > OVCAP) on = OVCAP;
    for (int t = 0; t < on; ++t) {
      int4 o = ovf[t];
      if (o.y == node) {
        const float4 xa = h4load(xw + (size_t)o.x * 64 + l * 4);
        float v = __int_as_float(o.z);
        if (FOLD) v *= dinv[o.x];
        acc.x = fmaf(xa.x, v, acc.x); acc.y = fmaf(xa.y, v, acc.y);
        acc.z = fmaf(xa.z, v, acc.z); acc.w = fmaf(xa.w, v, acc.w);
      }
    }
  }
  // self-loop (weight 1, scaled by selfw; outer *dinv[dst] completes dinv^2)
  const float4 xs = h4load(xw + (size_t)node * 64 + l * 4);
  acc.x = fmaf(xs.x, selfw, acc.x); acc.y = fmaf(xs.y, selfw, acc.y);
  acc.z = fmaf(xs.z, selfw, acc.z); acc.w = fmaf(xs.w, selfw, acc.w);
  return acc;
}

// ---------------- fused layer-1 gather + GEMM2 (xw -> xw2) ----------------

__global__ __launch_bounds__(256) void k_gather_gemm2(const __half* __restrict__ xw,
                                                      const float* __restrict__ dinv,
                                                      const int* __restrict__ cnt,
                                                      const int2* __restrict__ bucket,
                                                      const int4* __restrict__ ovf,
                                                      const int* __restrict__ ovf_n,
                                                      const float* __restrict__ b1,
                                                      const float* __restrict__ W2,
                                                      __half* __restrict__ Y) {
  __shared__ _Float16 ldsB[4096];
  __shared__ _Float16 ldsR[16 * 72];
  __shared__ float sdi[16];
  stage_B_lds(W2, ldsB);

  int l = threadIdx.x & 15;
  int g = threadIdx.x >> 4;
  int node = blockIdx.x * 16 + g;
  float di = dinv[node];
  float4 acc = gather_node<true>(xw, cnt, bucket, ovf, ovf_n, dinv, node, l, di);
  const float4 b4 = *(const float4*)(b1 + l * 4);
  _Float16* rp = &ldsR[g * 72 + l * 4];
  rp[0] = (_Float16)fmaxf(fmaf(acc.x, di, b4.x), 0.f);
  rp[1] = (_Float16)fmaxf(fmaf(acc.y, di, b4.y), 0.f);
  rp[2] = (_Float16)fmaxf(fmaf(acc.z, di, b4.z), 0.f);
  rp[3] = (_Float16)fmaxf(fmaf(acc.w, di, b4.w), 0.f);
  if (l == 0) sdi[g] = di;
  __syncthreads();

  int lane = threadIdx.x & 63;
  int l15 = lane & 15, q = lane >> 4;
  int t = threadIdx.x >> 6;  // this wave's col-tile
  half8 a0 = *(half8*)&ldsR[l15 * 72 + q * 8];
  half8 a1 = *(half8*)&ldsR[l15 * 72 + 32 + q * 8];
  half8 bf0 = *(half8*)&ldsB[((t * 2 + 0) * 64 + lane) * 8];
  half8 bf1 = *(half8*)&ldsB[((t * 2 + 1) * 64 + lane) * 8];
  f32x4 acc2 = {0.f, 0.f, 0.f, 0.f};
  acc2 = __builtin_amdgcn_mfma_f32_16x16x32_f16(a0, bf0, acc2, 0, 0, 0);
  acc2 = __builtin_amdgcn_mfma_f32_16x16x32_f16(a1, bf1, acc2, 0, 0, 0);
#pragma unroll
  for (int r = 0; r < 4; ++r) {
    int rw = blockIdx.x * 16 + q * 4 + r;
    float dv = sdi[q * 4 + r];
    Y[(size_t)rw * 64 + t * 16 + l15] = __float2half(acc2[r] * dv);
  }
}

// ---------------- layer-2 aggregation + heads + per-block max partial ----------------

__global__ __launch_bounds__(256) void k_gather_l2_heads(const __half* __restrict__ xw2,
                                                         const float* __restrict__ dinv,
                                                         const int* __restrict__ cnt,
                                                         const int2* __restrict__ bucket,
                                                         const int4* __restrict__ ovf,
                                                         const int* __restrict__ ovf_n,
                                                         const float* __restrict__ b2,
                                                         const float* __restrict__ Wn,
                                                         const float* __restrict__ bn,
                                                         const float* __restrict__ Wr,
                                                         const float* __restrict__ br,
                                                         float* __restrict__ logits,
                                                         float* __restrict__ rr,
                                                         float* __restrict__ part) {
  __shared__ float s[256];
  int l = threadIdx.x & 15;
  int node = blockIdx.x * 16 + (threadIdx.x >> 4);
  float4 acc = gather_node<false>(xw2, cnt, bucket, ovf, ovf_n, dinv, node, l, 1.0f);
  float di = dinv[node];
  const float4 b4 = *(const float4*)(b2 + l * 4);
  float4 r;
  r.x = fmaxf(fmaf(acc.x, di, b4.x), 0.f); r.y = fmaxf(fmaf(acc.y, di, b4.y), 0.f);
  r.z = fmaxf(fmaf(acc.z, di, b4.z), 0.f); r.w = fmaxf(fmaf(acc.w, di, b4.w), 0.f);
  const float4 wn4 = *(const float4*)(Wn + l * 4);
  const float4 wr4 = *(const float4*)(Wr + l * 4);
  float an = r.x * wn4.x + r.y * wn4.y + r.z * wn4.z + r.w * wn4.w;
  float ar = r.x * wr4.x + r.y * wr4.y + r.z * wr4.z + r.w * wr4.w;
#pragma unroll
  for (int m = 8; m > 0; m >>= 1) {
    an += __shfl_xor(an, m, 64);
    ar += __shfl_xor(ar, m, 64);
  }
  float lg = an + bn[0];
  if (l == 0) {
    logits[node] = lg;
    float xr = ar + br[0];
    rr[node] = 0.01f / (1.0f + expf(-xr));
  }
  // block max of 16 logits (dups across lanes are harmless)
  s[threadIdx.x] = lg;
  __syncthreads();
  for (int w = 128; w > 0; w >>= 1) {
    if (threadIdx.x < w) s[threadIdx.x] = fmaxf(s[threadIdx.x], s[threadIdx.x + w]);
    __syncthreads();
  }
  if (threadIdx.x == 0) part[blockIdx.x] = s[0];
}

// ---------------- softmax: per-block global-max re-reduce + exp + atomic sum ----------------

__global__ __launch_bounds__(256) void k_sexp(const float* __restrict__ logits,
                                              const float* __restrict__ part,
                                              float* __restrict__ sel,
                                              float* __restrict__ gsum) {
  __shared__ float s[256];
  float m = -INFINITY;
  for (int i = threadIdx.x; i < NTILE; i += 256) m = fmaxf(m, part[i]);
  s[threadIdx.x] = m;
  __syncthreads();
  for (int w = 128; w > 0; w >>= 1) {
    if (threadIdx.x < w) s[threadIdx.x] = fmaxf(s[threadIdx.x], s[threadIdx.x + w]);
    __syncthreads();
  }
  float gm = s[0];
  __syncthreads();
  float acc = 0.0f;
  for (int i = blockIdx.x * 256 + threadIdx.x; i < NN; i += RB * 256) {
    float e = expf(logits[i] - gm);
    sel[i] = e;
    acc += e;
  }
  s[threadIdx.x] = acc;
  __syncthreads();
  for (int w = 128; w > 0; w >>= 1) {
    if (threadIdx.x < w) s[threadIdx.x] += s[threadIdx.x + w];
    __syncthreads();
  }
  if (threadIdx.x == 0) unsafeAtomicAdd(gsum, s[0]);  // 256 funnel atomics ~4us
}

__global__ __launch_bounds__(256) void k_snorm(float* __restrict__ sel,
                                               const float* __restrict__ gsum) {
  int i = blockIdx.x * 256 + threadIdx.x;
  if (i < NN) sel[i] *= (1.0f / gsum[0]);
}

// ---------------- launch ----------------

extern "C" void kernel_launch(void* const* d_in, const int* in_sizes, int n_in,
                              void* d_out, int out_size, void* d_ws, size_t ws_size,
                              hipStream_t stream) {
  const float* x  = (const float*)d_in[0];
  const int*   ei = (const int*)d_in[1];   // [2, E]: src row then dst row
  const float* ew = (const float*)d_in[2];
  const float* W1 = (const float*)d_in[3];
  const float* b1 = (const float*)d_in[4];
  const float* W2 = (const float*)d_in[5];
  const float* b2 = (const float*)d_in[6];
  const float* Wn = (const float*)d_in[7];
  const float* bn = (const float*)d_in[8];
  const float* Wr = (const float*)d_in[9];
  const float* br = (const float*)d_in[10];
  const int* src = ei;
  const int* dst = ei + NE;

  // ws layout (byte offsets, all regions 16B-aligned)
  char* wsb = (char*)d_ws;
  __half* xw     = (__half*)wsb;                        // 12,800,000 B (layer-1 features, UNFOLDED)
  __half* xw2    = (__half*)(wsb + 12800000);           // 12,800,000 B (layer-2 features, prefolded)
  float*  logits = (float*)(wsb + 25600000);            // 400,000 B
  float*  dinv   = (float*)(wsb + 26000000);            // 400,000 B
  int2*   bucket = (int2*)(wsb + 26400000);             // 25,600,000 B
  int4*   ovf    = (int4*)(wsb + 52000000);             // 65,536 B
  int*    cnt    = (int*)(wsb + 52065536);              // 400,000 B -- memset from here
  int*    ovf_n  = (int*)(wsb + 52465536);              // 4 B
  float*  gsum   = (float*)(wsb + 52465540);            // 4 B       -- memset to here
  float*  part1  = (float*)(wsb + 52465544);            // 25,000 B (6250 floats)

  float* sel = (float*)d_out;                           // node_selector [N]
  float* rr  = (float*)d_out + NN;                      // rescue_ratios [N]

  int gN = (NN + 255) / 256;

  // zero cnt + ovf_n + gsum in one memset
  hipMemsetAsync(cnt, 0, (size_t)(NN + 2) * 4, stream);

  // ---- fused bucket build + GEMM1 (scatter latency hides the MFMA work) ----
  k_bucket_gemm1<<<GB1 + NEB, 256, 0, stream>>>(src, dst, ew, x, W1,
                                                cnt, bucket, ovf, ovf_n, xw);

  // ---- dinv from bucket weights (no per-edge atomics anywhere) ----
  k_dinv<<<(NN + 63) / 64, 256, 0, stream>>>(cnt, bucket, ovf, ovf_n, dinv);

  // ---- fused layer-1 gather (dinv[src] folded per edge) + gemm2: xw -> xw2 ----
  k_gather_gemm2<<<NTILE, 256, 0, stream>>>(xw, dinv, cnt, bucket, ovf, ovf_n,
                                            b1, W2, xw2);

  // ---- layer 2 gather + heads + max partials ----
  k_gather_l2_heads<<<NTILE, 256, 0, stream>>>(xw2, dinv, cnt, bucket, ovf, ovf_n,
                                               b2, Wn, bn, Wr, br, logits, rr, part1);

  // ---- softmax ----
  k_sexp<<<RB, 256, 0, stream>>>(logits, part1, sel, gsum);
  k_snorm<<<gN, 256, 0, stream>>>(sel, gsum);
}

// Round 3
// 215.292 us; speedup vs baseline: 1.2287x; 1.0584x over previous
//
#include <hip/hip_runtime.h>
#include <hip/hip_fp16.h>
#include <math.h>

#define NN 100000
#define NE 1000000
#define CAP 32        // bucket capacity per node; degrees ~Poisson(10), max ~27
#define OVCAP 4096    // overflow list capacity (correct fallback, ~never used)
#define NEB 3907      // ceil(NE/256) bucket blocks
#define NT32 3125     // NN/32 gather blocks (32 nodes/block, 8 lanes/node)
#define RB 256        // softmax reduction grid
#define GB1 512       // GEMM-role blocks inside the fused kernel
// H = 64. R20/R22: bucket scatter is latency-bound -> GEMM1 hidden under it
// via block-role fusion (fused kernel at scatter floor ~71us, MfmaUtil free).
// R21 LESSON: per-edge deg atomic cost ~30us; dinv recovered from buckets.
// R23: gathers are MLP-starved (141MB cached reads at only 2TB/s, VALU <3us)
// -> 8 lanes/node with dwordx4 row loads: 2x independent node streams/wave,
// half the load instructions. Dense 4-deep unroll retained (R16).
// R14 LESSON: gather input and GEMM output must be DISTINCT buffers.

typedef _Float16 half8 __attribute__((ext_vector_type(8)));
typedef float f32x4 __attribute__((ext_vector_type(4)));

// ---------------- W staging: fragment layout in LDS (k=(s*32+q*8+j), n=t*16+l15) ----------------

__device__ __forceinline__ void stage_B_lds(const float* __restrict__ W,
                                            _Float16* __restrict__ ldsB) {
  for (int u = threadIdx.x; u < 512; u += 256) {
    int slane = u & 63, ts = u >> 6;
    int t = ts >> 1, s = ts & 1;
    int qq = slane >> 4, ll = slane & 15;
#pragma unroll
    for (int j = 0; j < 8; ++j)
      ldsB[u * 8 + j] = (_Float16)W[(s * 32 + qq * 8 + j) * 64 + t * 16 + ll];
  }
}

// ---------------- fused bucket build + GEMM1 ----------------
// blocks [0,GB1): xw = X@W1 (fp16, UNFOLDED — no bucket dependency)
// blocks [GB1, GB1+NEB): edge scatter into buckets (ONE atomic + one 8B store
// per edge — the measured-floor form).

__global__ __launch_bounds__(256) void k_bucket_gemm1(const int* __restrict__ src,
                                                      const int* __restrict__ dst,
                                                      const float* __restrict__ ew,
                                                      const float* __restrict__ X,
                                                      const float* __restrict__ W1,
                                                      int* __restrict__ cnt,
                                                      int2* __restrict__ bucket,
                                                      int4* __restrict__ ovf,
                                                      int* __restrict__ ovf_n,
                                                      __half* __restrict__ Y) {
  __shared__ _Float16 ldsB[4096];
  if (blockIdx.x >= GB1) {
    // ---- bucket role ----
    int e = (blockIdx.x - GB1) * 256 + threadIdx.x;
    if (e < NE) {
      int s = src[e];
      int d = dst[e];
      float w = ew[e];
      int pos = atomicAdd(&cnt[d], 1);
      if (pos < CAP) {
        bucket[d * CAP + pos] = make_int2(s, __float_as_int(w));
      } else {
        int t = atomicAdd(ovf_n, 1);
        if (t < OVCAP) ovf[t] = make_int4(s, d, __float_as_int(w), 0);
      }
    }
    return;
  }
  // ---- GEMM role: 16x16x32_f16; A: m=lane&15, k=(lane>>4)*8+j;
  // C/D: col=lane&15, row=q*4+reg [m89-verified] ----
  stage_B_lds(W1, ldsB);
  __syncthreads();
  int lane = threadIdx.x & 63;
  int l15 = lane & 15, q = lane >> 4;
  half8 bfr[4][2];
#pragma unroll
  for (int t = 0; t < 4; ++t)
#pragma unroll
    for (int s = 0; s < 2; ++s)
      bfr[t][s] = *(half8*)&ldsB[((t * 2 + s) * 64 + lane) * 8];

  int wid = blockIdx.x * 4 + (threadIdx.x >> 6);
  for (int tile = wid; tile < NN / 16; tile += GB1 * 4) {
    int row = tile * 16 + l15;
    f32x4 acc[4] = {{0.f,0.f,0.f,0.f},{0.f,0.f,0.f,0.f},
                    {0.f,0.f,0.f,0.f},{0.f,0.f,0.f,0.f}};
#pragma unroll
    for (int s = 0; s < 2; ++s) {
      const float* ap = X + (size_t)row * 64 + s * 32 + q * 8;
      float4 a0 = *(const float4*)ap;
      float4 a1 = *(const float4*)(ap + 4);
      half8 af;
      af[0] = (_Float16)a0.x; af[1] = (_Float16)a0.y;
      af[2] = (_Float16)a0.z; af[3] = (_Float16)a0.w;
      af[4] = (_Float16)a1.x; af[5] = (_Float16)a1.y;
      af[6] = (_Float16)a1.z; af[7] = (_Float16)a1.w;
#pragma unroll
      for (int t = 0; t < 4; ++t)
        acc[t] = __builtin_amdgcn_mfma_f32_16x16x32_f16(af, bfr[t][s], acc[t], 0, 0, 0);
    }
#pragma unroll
    for (int r = 0; r < 4; ++r) {
      int rw = tile * 16 + q * 4 + r;
#pragma unroll
      for (int t = 0; t < 4; ++t)
        Y[(size_t)rw * 64 + t * 16 + l15] = __float2half(acc[t][r]);
    }
  }
}

// ---------------- dinv from bucket weights: 4 lanes/node, int4 reads ----------------

__global__ __launch_bounds__(256) void k_dinv(const int* __restrict__ cnt,
                                              const int2* __restrict__ bucket,
                                              const int4* __restrict__ ovf,
                                              const int* __restrict__ ovf_n,
                                              float* __restrict__ dinv) {
  int t = threadIdx.x & 3;
  int node = blockIdx.x * 64 + (threadIdx.x >> 2);
  if (node >= NN) return;
  int c = cnt[node];
  int cc = c < CAP ? c : CAP;
  int nq = (cc + 1) >> 1;  // int4 chunks in use (2 edges each)
  const int4* bk4 = (const int4*)(bucket + (size_t)node * CAP);
  float dsum = 0.f;
  for (int j = t; j < nq; j += 4) {
    int4 qv = bk4[j];
    int e0 = 2 * j, e1 = 2 * j + 1;
    if (e0 < cc) dsum += __int_as_float(qv.y);
    if (e1 < cc) dsum += __int_as_float(qv.w);
  }
  dsum += __shfl_xor(dsum, 1, 64);
  dsum += __shfl_xor(dsum, 2, 64);
  if (t == 0) {
    float tot = dsum + 1.0f;  // self-loop weight 1
    if (c > CAP) {
      int on = ovf_n[0]; if (on > OVCAP) on = OVCAP;
      for (int k = 0; k < on; ++k) {
        int4 o = ovf[k];
        if (o.y == node) tot += __int_as_float(o.z);
      }
    }
    dinv[node] = 1.0f / sqrtf(tot);
  }
}

// ---------------- gather core: 8 lanes/node, dwordx4 fp16 row loads ----------------
// FOLD=true: per-edge weight *= dinv[src] (layer-1; xw unfolded), self term
// scaled by selfw=dinv[node]. FOLD=false: weights raw (layer-2; xw2 prefolded).

__device__ __forceinline__ void h8load(const __half* p, float4& a, float4& b) {
  float4 raw = *(const float4*)p;  // 8 halfs in one dwordx4 (16B aligned)
  __half2 h0 = *(__half2*)&raw.x;
  __half2 h1 = *(__half2*)&raw.y;
  __half2 h2 = *(__half2*)&raw.z;
  __half2 h3 = *(__half2*)&raw.w;
  float2 f0 = __half22float2(h0), f1 = __half22float2(h1);
  float2 f2 = __half22float2(h2), f3 = __half22float2(h3);
  a = make_float4(f0.x, f0.y, f1.x, f1.y);
  b = make_float4(f2.x, f2.y, f3.x, f3.y);
}

#define FMA8(xa, xb, v) do { \
  A.x = fmaf((xa).x, (v), A.x); A.y = fmaf((xa).y, (v), A.y); \
  A.z = fmaf((xa).z, (v), A.z); A.w = fmaf((xa).w, (v), A.w); \
  B.x = fmaf((xb).x, (v), B.x); B.y = fmaf((xb).y, (v), B.y); \
  B.z = fmaf((xb).z, (v), B.z); B.w = fmaf((xb).w, (v), B.w); } while (0)

template <bool FOLD>
__device__ __forceinline__ void gather_node8(const __half* __restrict__ xw,
                                             const int* __restrict__ cnt,
                                             const int2* __restrict__ bucket,
                                             const int4* __restrict__ ovf,
                                             const int* __restrict__ ovf_n,
                                             const float* __restrict__ dinv,
                                             int node, int l, float selfw,
                                             float4& A, float4& B) {
  int c = cnt[node];
  int cc = c < CAP ? c : CAP;
  const int4* bk4 = (const int4*)(bucket + (size_t)node * CAP);
  A = make_float4(0.f, 0.f, 0.f, 0.f);
  B = make_float4(0.f, 0.f, 0.f, 0.f);

  int j = 0;
  for (; j + 4 <= cc; j += 4) {
    int4 pa = bk4[j >> 1];
    int4 pb = bk4[(j >> 1) + 1];
    float4 xa0, xb0, xa1, xb1, xa2, xb2, xa3, xb3;
    h8load(xw + (size_t)pa.x * 64 + l * 8, xa0, xb0);
    h8load(xw + (size_t)pa.z * 64 + l * 8, xa1, xb1);
    h8load(xw + (size_t)pb.x * 64 + l * 8, xa2, xb2);
    h8load(xw + (size_t)pb.z * 64 + l * 8, xa3, xb3);
    float v0 = __int_as_float(pa.y);
    float v1 = __int_as_float(pa.w);
    float v2 = __int_as_float(pb.y);
    float v3 = __int_as_float(pb.w);
    if (FOLD) {
      v0 *= dinv[pa.x]; v1 *= dinv[pa.z];
      v2 *= dinv[pb.x]; v3 *= dinv[pb.z];
    }
    FMA8(xa0, xb0, v0);
    FMA8(xa1, xb1, v1);
    FMA8(xa2, xb2, v2);
    FMA8(xa3, xb3, v3);
  }
  const int2* bk = (const int2*)bk4;
  for (; j < cc; ++j) {
    int2 E = bk[j];
    float4 xa, xb;
    h8load(xw + (size_t)E.x * 64 + l * 8, xa, xb);
    float v = __int_as_float(E.y);
    if (FOLD) v *= dinv[E.x];
    FMA8(xa, xb, v);
  }
  if (c > CAP) {
    int on = ovf_n[0]; if (on > OVCAP) on = OVCAP;
    for (int t = 0; t < on; ++t) {
      int4 o = ovf[t];
      if (o.y == node) {
        float4 xa, xb;
        h8load(xw + (size_t)o.x * 64 + l * 8, xa, xb);
        float v = __int_as_float(o.z);
        if (FOLD) v *= dinv[o.x];
        FMA8(xa, xb, v);
      }
    }
  }
  // self-loop (weight 1, scaled by selfw; outer *dinv[dst] completes dinv^2)
  {
    float4 xs, ys;
    h8load(xw + (size_t)node * 64 + l * 8, xs, ys);
    FMA8(xs, ys, selfw);
  }
}

#undef FMA8

// ---------------- fused layer-1 gather + GEMM2 (xw -> xw2), 32 nodes/block ----------------

__global__ __launch_bounds__(256) void k_gather_gemm2(const __half* __restrict__ xw,
                                                      const float* __restrict__ dinv,
                                                      const int* __restrict__ cnt,
                                                      const int2* __restrict__ bucket,
                                                      const int4* __restrict__ ovf,
                                                      const int* __restrict__ ovf_n,
                                                      const float* __restrict__ b1,
                                                      const float* __restrict__ W2,
                                                      __half* __restrict__ Y) {
  __shared__ _Float16 ldsB[4096];
  __shared__ _Float16 ldsR[32 * 72];
  __shared__ float sdi[32];
  stage_B_lds(W2, ldsB);

  int l = threadIdx.x & 7;
  int g = threadIdx.x >> 3;            // 0..31
  int node = blockIdx.x * 32 + g;
  float di = dinv[node];
  float4 A, Bv;
  gather_node8<true>(xw, cnt, bucket, ovf, ovf_n, dinv, node, l, di, A, Bv);
  const float4 ba = *(const float4*)(b1 + l * 8);
  const float4 bb = *(const float4*)(b1 + l * 8 + 4);
  _Float16* rp = &ldsR[g * 72 + l * 8];
  rp[0] = (_Float16)fmaxf(fmaf(A.x,  di, ba.x), 0.f);
  rp[1] = (_Float16)fmaxf(fmaf(A.y,  di, ba.y), 0.f);
  rp[2] = (_Float16)fmaxf(fmaf(A.z,  di, ba.z), 0.f);
  rp[3] = (_Float16)fmaxf(fmaf(A.w,  di, ba.w), 0.f);
  rp[4] = (_Float16)fmaxf(fmaf(Bv.x, di, bb.x), 0.f);
  rp[5] = (_Float16)fmaxf(fmaf(Bv.y, di, bb.y), 0.f);
  rp[6] = (_Float16)fmaxf(fmaf(Bv.z, di, bb.z), 0.f);
  rp[7] = (_Float16)fmaxf(fmaf(Bv.w, di, bb.w), 0.f);
  if (l == 0) sdi[g] = di;
  __syncthreads();

  int lane = threadIdx.x & 63;
  int l15 = lane & 15, q = lane >> 4;
  int t = threadIdx.x >> 6;  // this wave's col-tile
  half8 bf0 = *(half8*)&ldsB[((t * 2 + 0) * 64 + lane) * 8];
  half8 bf1 = *(half8*)&ldsB[((t * 2 + 1) * 64 + lane) * 8];
#pragma unroll
  for (int rt = 0; rt < 2; ++rt) {
    half8 a0 = *(half8*)&ldsR[(rt * 16 + l15) * 72 + q * 8];
    half8 a1 = *(half8*)&ldsR[(rt * 16 + l15) * 72 + 32 + q * 8];
    f32x4 acc2 = {0.f, 0.f, 0.f, 0.f};
    acc2 = __builtin_amdgcn_mfma_f32_16x16x32_f16(a0, bf0, acc2, 0, 0, 0);
    acc2 = __builtin_amdgcn_mfma_f32_16x16x32_f16(a1, bf1, acc2, 0, 0, 0);
#pragma unroll
    for (int r = 0; r < 4; ++r) {
      int rw = blockIdx.x * 32 + rt * 16 + q * 4 + r;
      float dv = sdi[rt * 16 + q * 4 + r];
      Y[(size_t)rw * 64 + t * 16 + l15] = __float2half(acc2[r] * dv);
    }
  }
}

// ---------------- layer-2 aggregation + heads + per-block max partial ----------------

__global__ __launch_bounds__(256) void k_gather_l2_heads(const __half* __restrict__ xw2,
                                                         const float* __restrict__ dinv,
                                                         const int* __restrict__ cnt,
                                                         const int2* __restrict__ bucket,
                                                         const int4* __restrict__ ovf,
                                                         const int* __restrict__ ovf_n,
                                                         const float* __restrict__ b2,
                                                         const float* __restrict__ Wn,
                                                         const float* __restrict__ bn,
                                                         const float* __restrict__ Wr,
                                                         const float* __restrict__ br,
                                                         float* __restrict__ logits,
                                                         float* __restrict__ rr,
                                                         float* __restrict__ part) {
  __shared__ float s[256];
  int l = threadIdx.x & 7;
  int node = blockIdx.x * 32 + (threadIdx.x >> 3);
  float4 A, Bv;
  gather_node8<false>(xw2, cnt, bucket, ovf, ovf_n, dinv, node, l, 1.0f, A, Bv);
  float di = dinv[node];
  const float4 ba = *(const float4*)(b2 + l * 8);
  const float4 bb = *(const float4*)(b2 + l * 8 + 4);
  float r0 = fmaxf(fmaf(A.x,  di, ba.x), 0.f);
  float r1 = fmaxf(fmaf(A.y,  di, ba.y), 0.f);
  float r2 = fmaxf(fmaf(A.z,  di, ba.z), 0.f);
  float r3 = fmaxf(fmaf(A.w,  di, ba.w), 0.f);
  float r4 = fmaxf(fmaf(Bv.x, di, bb.x), 0.f);
  float r5 = fmaxf(fmaf(Bv.y, di, bb.y), 0.f);
  float r6 = fmaxf(fmaf(Bv.z, di, bb.z), 0.f);
  float r7 = fmaxf(fmaf(Bv.w, di, bb.w), 0.f);
  const float4 wna = *(const float4*)(Wn + l * 8);
  const float4 wnb = *(const float4*)(Wn + l * 8 + 4);
  const float4 wra = *(const float4*)(Wr + l * 8);
  const float4 wrb = *(const float4*)(Wr + l * 8 + 4);
  float an = r0 * wna.x + r1 * wna.y + r2 * wna.z + r3 * wna.w
           + r4 * wnb.x + r5 * wnb.y + r6 * wnb.z + r7 * wnb.w;
  float ar = r0 * wra.x + r1 * wra.y + r2 * wra.z + r3 * wra.w
           + r4 * wrb.x + r5 * wrb.y + r6 * wrb.z + r7 * wrb.w;
#pragma unroll
  for (int m = 4; m > 0; m >>= 1) {
    an += __shfl_xor(an, m, 64);
    ar += __shfl_xor(ar, m, 64);
  }
  float lg = an + bn[0];
  if (l == 0) {
    logits[node] = lg;
    float xr = ar + br[0];
    rr[node] = 0.01f / (1.0f + expf(-xr));
  }
  // block max of 32 logits (dups across lanes are harmless)
  s[threadIdx.x] = lg;
  __syncthreads();
  for (int w = 128; w > 0; w >>= 1) {
    if (threadIdx.x < w) s[threadIdx.x] = fmaxf(s[threadIdx.x], s[threadIdx.x + w]);
    __syncthreads();
  }
  if (threadIdx.x == 0) part[blockIdx.x] = s[0];
}

// ---------------- softmax: per-block global-max re-reduce + exp + atomic sum ----------------

__global__ __launch_bounds__(256) void k_sexp(const float* __restrict__ logits,
                                              const float* __restrict__ part,
                                              float* __restrict__ sel,
                                              float* __restrict__ gsum) {
  __shared__ float s[256];
  float m = -INFINITY;
  for (int i = threadIdx.x; i < NT32; i += 256) m = fmaxf(m, part[i]);
  s[threadIdx.x] = m;
  __syncthreads();
  for (int w = 128; w > 0; w >>= 1) {
    if (threadIdx.x < w) s[threadIdx.x] = fmaxf(s[threadIdx.x], s[threadIdx.x + w]);
    __syncthreads();
  }
  float gm = s[0];
  __syncthreads();
  float acc = 0.0f;
  for (int i = blockIdx.x * 256 + threadIdx.x; i < NN; i += RB * 256) {
    float e = expf(logits[i] - gm);
    sel[i] = e;
    acc += e;
  }
  s[threadIdx.x] = acc;
  __syncthreads();
  for (int w = 128; w > 0; w >>= 1) {
    if (threadIdx.x < w) s[threadIdx.x] += s[threadIdx.x + w];
    __syncthreads();
  }
  if (threadIdx.x == 0) unsafeAtomicAdd(gsum, s[0]);  // 256 funnel atomics ~4us
}

__global__ __launch_bounds__(256) void k_snorm(float* __restrict__ sel,
                                               const float* __restrict__ gsum) {
  int i = blockIdx.x * 256 + threadIdx.x;
  if (i < NN) sel[i] *= (1.0f / gsum[0]);
}

// ---------------- launch ----------------

extern "C" void kernel_launch(void* const* d_in, const int* in_sizes, int n_in,
                              void* d_out, int out_size, void* d_ws, size_t ws_size,
                              hipStream_t stream) {
  const float* x  = (const float*)d_in[0];
  const int*   ei = (const int*)d_in[1];   // [2, E]: src row then dst row
  const float* ew = (const float*)d_in[2];
  const float* W1 = (const float*)d_in[3];
  const float* b1 = (const float*)d_in[4];
  const float* W2 = (const float*)d_in[5];
  const float* b2 = (const float*)d_in[6];
  const float* Wn = (const float*)d_in[7];
  const float* bn = (const float*)d_in[8];
  const float* Wr = (const float*)d_in[9];
  const float* br = (const float*)d_in[10];
  const int* src = ei;
  const int* dst = ei + NE;

  // ws layout (byte offsets, all regions 16B-aligned)
  char* wsb = (char*)d_ws;
  __half* xw     = (__half*)wsb;                        // 12,800,000 B (layer-1 features, UNFOLDED)
  __half* xw2    = (__half*)(wsb + 12800000);           // 12,800,000 B (layer-2 features, prefolded)
  float*  logits = (float*)(wsb + 25600000);            // 400,000 B
  float*  dinv   = (float*)(wsb + 26000000);            // 400,000 B
  int2*   bucket = (int2*)(wsb + 26400000);             // 25,600,000 B
  int4*   ovf    = (int4*)(wsb + 52000000);             // 65,536 B
  int*    cnt    = (int*)(wsb + 52065536);              // 400,000 B -- memset from here
  int*    ovf_n  = (int*)(wsb + 52465536);              // 4 B
  float*  gsum   = (float*)(wsb + 52465540);            // 4 B       -- memset to here
  float*  part1  = (float*)(wsb + 52465544);            // 12,500 B (3125 floats)

  float* sel = (float*)d_out;                           // node_selector [N]
  float* rr  = (float*)d_out + NN;                      // rescue_ratios [N]

  int gN = (NN + 255) / 256;

  // zero cnt + ovf_n + gsum in one memset
  hipMemsetAsync(cnt, 0, (size_t)(NN + 2) * 4, stream);

  // ---- fused bucket build + GEMM1 (scatter latency hides the MFMA work) ----
  k_bucket_gemm1<<<GB1 + NEB, 256, 0, stream>>>(src, dst, ew, x, W1,
                                                cnt, bucket, ovf, ovf_n, xw);

  // ---- dinv from bucket weights (no per-edge atomics anywhere) ----
  k_dinv<<<(NN + 63) / 64, 256, 0, stream>>>(cnt, bucket, ovf, ovf_n, dinv);

  // ---- fused layer-1 gather (dinv[src] folded per edge) + gemm2: xw -> xw2 ----
  k_gather_gemm2<<<NT32, 256, 0, stream>>>(xw, dinv, cnt, bucket, ovf, ovf_n,
                                           b1, W2, xw2);

  // ---- layer 2 gather + heads + max partials ----
  k_gather_l2_heads<<<NT32, 256, 0, stream>>>(xw2, dinv, cnt, bucket, ovf, ovf_n,
                                              b2, Wn, bn, Wr, br, logits, rr, part1);

  // ---- softmax ----
  k_sexp<<<RB, 256, 0, stream>>>(logits, part1, sel, gsum);
  k_snorm<<<gN, 256, 0, stream>>>(sel, gsum);
}